// Round 2
// baseline (189.637 us; speedup 1.0000x reference)
//
#include <hip/hip_runtime.h>
#include <math.h>

#define NC 100
#define ND 384
#define NB 4096
#define NPAIR (NC * NC)                 // 10000
#define PAIR_BLOCKS ((NPAIR + 3) / 4)   // 2500 (4 waves/block, 1 pair/wave)
#define PRES_BLOCKS (NB / 256)          // 16

// ---- K1: init accumulators (d_out / d_ws are poisoned 0xAA every launch) ----
__global__ void init_kernel(unsigned* __restrict__ cmin,
                            unsigned* __restrict__ mask,
                            float* __restrict__ out) {
  int t = threadIdx.x;  // 128
  if (t < NC) cmin[t] = 0x7F800000u;  // +inf bit pattern
  if (t == 100) { mask[0] = 0u; mask[1] = 0u; mask[2] = 0u; mask[3] = 0u; }
  if (t == 101) *out = 0.f;
}

// ---- K2: fused setup. blockIdx roles:
//   [0,100)            per-class prep: wc=2^w, a=wc*c, tcc=sum wc*c^2
//   [100,100+2500)     cdist pairs: wave-per-(i,j), atomicMin(cmin[i], d2)
//   [2600,2616)        presence bitmask
__global__ __launch_bounds__(256) void setup_kernel(
    const float* __restrict__ centers, const float* __restrict__ cw,
    const int* __restrict__ targets, float* __restrict__ wc,
    float* __restrict__ a, float* __restrict__ tcc,
    unsigned* __restrict__ cmin, unsigned* __restrict__ mask) {
  int b = blockIdx.x;
  int tid = threadIdx.x;
  if (b < NC) {
    int k = b;
    float part = 0.f;
    for (int d = tid; d < ND; d += 256) {
      float c = centers[k * ND + d];
      float w = exp2f(cw[k * ND + d]);
      wc[k * ND + d] = w;
      a[k * ND + d] = w * c;
      part = fmaf(w * c, c, part);
    }
    #pragma unroll
    for (int off = 32; off; off >>= 1) part += __shfl_xor(part, off, 64);
    __shared__ float s[4];
    if ((tid & 63) == 0) s[tid >> 6] = part;
    __syncthreads();
    if (tid == 0) tcc[k] = s[0] + s[1] + s[2] + s[3];
  } else if (b < NC + PAIR_BLOCKS) {
    int pid = (b - NC) * 4 + (tid >> 6);
    int lane = tid & 63;
    if (pid < NPAIR) {
      int i = pid / NC, j = pid - i * NC;
      float sacc = 0.f;
      #pragma unroll
      for (int e = 0; e < 3; e++) {
        int d = lane * 2 + 128 * e;
        float2 ci = *(const float2*)(centers + i * ND + d);
        float2 cj = *(const float2*)(centers + j * ND + d);
        float2 wi = *(const float2*)(cw + i * ND + d);
        float dfx = ci.x - cj.x, dfy = ci.y - cj.y;
        sacc = fmaf(exp2f(wi.x) * dfx, dfx, sacc);
        sacc = fmaf(exp2f(wi.y) * dfy, dfy, sacc);
      }
      #pragma unroll
      for (int off = 32; off; off >>= 1) sacc += __shfl_xor(sacc, off, 64);
      if (lane == 0 && i != j) atomicMin(&cmin[i], __float_as_uint(sacc));
    }
  } else {
    int idx = (b - NC - PAIR_BLOCKS) * 256 + tid;
    if (idx < NB) {
      int t = targets[idx];
      atomicOr(&mask[t >> 5], 1u << (t & 31));
    }
  }
}

// ---- K3: main — one wave per sample, k unrolled x4 (independent butterflies) ----
__global__ __launch_bounds__(256) void main_kernel(
    const float* __restrict__ x, const int* __restrict__ targets,
    const float* __restrict__ wc, const float* __restrict__ a,
    const float* __restrict__ tcc, const unsigned* __restrict__ cmin,
    const unsigned* __restrict__ mask, float* __restrict__ out) {
  int wave = threadIdx.x >> 6;
  int lane = threadIdx.x & 63;
  int i = blockIdx.x * 4 + wave;
  int ti = targets[i];

  float2 x2[3], m2x[3];
  #pragma unroll
  for (int e = 0; e < 3; e++) {
    float2 v = *(const float2*)(x + i * ND + lane * 2 + 128 * e);
    x2[e] = make_float2(v.x * v.x, v.y * v.y);
    m2x[e] = make_float2(-2.f * v.x, -2.f * v.y);
  }

  float best_an = 1e30f;
  float d_ap = 0.f;
  for (int k0 = 0; k0 < NC; k0 += 4) {
    float acc[4];
    #pragma unroll
    for (int u = 0; u < 4; u++) {
      int k = k0 + u;
      const float* wk = wc + k * ND + lane * 2;
      const float* ak = a + k * ND + lane * 2;
      float s = 0.f;
      #pragma unroll
      for (int e = 0; e < 3; e++) {
        float2 w = *(const float2*)(wk + 128 * e);
        float2 av = *(const float2*)(ak + 128 * e);
        s = fmaf(x2[e].x, w.x, s);
        s = fmaf(x2[e].y, w.y, s);
        s = fmaf(m2x[e].x, av.x, s);
        s = fmaf(m2x[e].y, av.y, s);
      }
      acc[u] = s;
    }
    // 4 independent 6-stage butterflies — ILP hides ds_bpermute latency
    #pragma unroll
    for (int off = 32; off; off >>= 1) {
      #pragma unroll
      for (int u = 0; u < 4; u++) acc[u] += __shfl_xor(acc[u], off, 64);
    }
    #pragma unroll
    for (int u = 0; u < 4; u++) {
      int k = k0 + u;
      float d2 = tcc[k] + acc[u];
      float dist = sqrtf(fmaxf(d2, 1e-12f));
      unsigned present = (mask[k >> 5] >> (k & 31)) & 1u;
      if (k == ti) d_ap = dist;
      else if (present) best_an = fminf(best_an, dist);
    }
  }

  float cc = sqrtf(__uint_as_float(cmin[ti]));
  float per = d_ap + ((best_an >= cc) ? 0.f : cc - best_an);

  __shared__ float s[4];
  if (lane == 0) s[wave] = per;
  __syncthreads();
  if (threadIdx.x == 0) {
    float t = s[0] + s[1] + s[2] + s[3];
    atomicAdd(out, t * (1.0f / NB));
  }
}

extern "C" void kernel_launch(void* const* d_in, const int* in_sizes, int n_in,
                              void* d_out, int out_size, void* d_ws, size_t ws_size,
                              hipStream_t stream) {
  const float* inputs  = (const float*)d_in[0];
  const int*   targets = (const int*)d_in[1];
  // d_in[2] = epoch_number (unused by the reference math)
  const float* centers = (const float*)d_in[3];
  const float* cw      = (const float*)d_in[4];
  float* out = (float*)d_out;

  float* wc    = (float*)d_ws;               // [NC*ND]
  float* a     = wc + NC * ND;               // [NC*ND]
  float* tcc   = a + NC * ND;                // [NC]
  unsigned* cmin = (unsigned*)(tcc + NC);    // [NC]
  unsigned* mask = cmin + NC;                // [4]

  init_kernel<<<1, 128, 0, stream>>>(cmin, mask, out);
  setup_kernel<<<NC + PAIR_BLOCKS + PRES_BLOCKS, 256, 0, stream>>>(
      centers, cw, targets, wc, a, tcc, cmin, mask);
  main_kernel<<<NB / 4, 256, 0, stream>>>(inputs, targets, wc, a, tcc, cmin,
                                          mask, out);
}

// Round 3
// 127.098 us; speedup vs baseline: 1.4921x; 1.4921x over previous
//
#include <hip/hip_runtime.h>
#include <math.h>

#define NC 100
#define ND 384
#define NB 4096
#define KS 4          // K-split factor
#define KT 96         // K per split (384/4)
#define MT 64         // samples per GEMM block
#define XP 100        // padded x-tile row (floats)
#define CPAD 33       // padded class-chunk row (floats)
#define PPAD 104      // padded partial row (floats)

// ================= Kernel A: setup (216 blocks x 256) =================
//  b in [0,100)    : prep class b -> wc=2^cw, a=wc*c, tcc=sum wc*c^2
//  b in [100,200)  : cdist[b-100] = sqrt(min_{j!=i} sum_d wc_i*(c_i-c_j)^2)
//  b in [200,216)  : presence: per-block local 128-bit mask (no global atomics)
__global__ __launch_bounds__(256) void setup_kernel(
    const float* __restrict__ centers, const float* __restrict__ cw,
    const int* __restrict__ targets, float* __restrict__ wc,
    float* __restrict__ a, float* __restrict__ tcc,
    float* __restrict__ cdist, unsigned* __restrict__ pres16,
    float* __restrict__ out) {
  __shared__ float sA[2 * ND + 16];
  int b = blockIdx.x;
  int tid = threadIdx.x;
  int wave = tid >> 6, lane = tid & 63;

  if (b < NC) {
    int k = b;
    if (b == 0 && tid == 255) out[0] = 0.f;  // d_out is poisoned each launch
    float part = 0.f;
    for (int d = tid; d < ND; d += 256) {
      float c = centers[k * ND + d];
      float w = exp2f(cw[k * ND + d]);
      wc[k * ND + d] = w;
      a[k * ND + d] = w * c;
      part = fmaf(w * c, c, part);
    }
    #pragma unroll
    for (int off = 32; off; off >>= 1) part += __shfl_xor(part, off, 64);
    if (lane == 0) sA[wave] = part;
    __syncthreads();
    if (tid == 0) tcc[k] = sA[0] + sA[1] + sA[2] + sA[3];
  } else if (b < 2 * NC) {
    int i = b - NC;
    float* ci_s = sA;
    float* wi_s = sA + ND;
    float* smin = sA + 2 * ND;
    for (int d = tid; d < ND; d += 256) {
      ci_s[d] = centers[i * ND + d];
      wi_s[d] = exp2f(cw[i * ND + d]);
    }
    __syncthreads();
    float minv = 1e30f;
    // wave handles j = wave + 4*s, s in [0,25); groups of 4 for ILP
    for (int s = 0; s < 24; s += 4) {
      float red[4];
      #pragma unroll
      for (int u = 0; u < 4; u++) {
        int j = wave + 4 * (s + u);
        float acc = 0.f;
        #pragma unroll
        for (int e = 0; e < 6; e++) {
          int d = lane + 64 * e;
          float df = ci_s[d] - centers[j * ND + d];
          acc = fmaf(wi_s[d] * df, df, acc);
        }
        red[u] = acc;
      }
      #pragma unroll
      for (int off = 32; off; off >>= 1) {
        #pragma unroll
        for (int u = 0; u < 4; u++) red[u] += __shfl_xor(red[u], off, 64);
      }
      #pragma unroll
      for (int u = 0; u < 4; u++) {
        int j = wave + 4 * (s + u);
        if (j != i) minv = fminf(minv, red[u]);
      }
    }
    {  // tail: s = 24 -> j = wave + 96
      int j = wave + 96;
      float acc = 0.f;
      #pragma unroll
      for (int e = 0; e < 6; e++) {
        int d = lane + 64 * e;
        float df = ci_s[d] - centers[j * ND + d];
        acc = fmaf(wi_s[d] * df, df, acc);
      }
      #pragma unroll
      for (int off = 32; off; off >>= 1) acc += __shfl_xor(acc, off, 64);
      if (j != i) minv = fminf(minv, acc);
    }
    if (lane == 0) smin[wave] = minv;
    __syncthreads();
    if (tid == 0)
      cdist[i] = sqrtf(fminf(fminf(smin[0], smin[1]), fminf(smin[2], smin[3])));
  } else {
    int pb = b - 2 * NC;
    unsigned* um = (unsigned*)sA;
    if (tid < 4) um[tid] = 0u;
    __syncthreads();
    int t = targets[pb * 256 + tid];
    atomicOr(&um[t >> 5], 1u << (t & 31));
    __syncthreads();
    if (tid < 4) pres16[pb * 4 + tid] = um[tid];
  }
}

// ========== Kernel B: vector GEMM, grid 257 (256 GEMM + 1 mask-merge) ==========
// block (mb, ks): samples [mb*64, mb*64+64), d-range [ks*96, ks*96+96)
// thread (sg=t>>5, cg=t&31): 8 samples {sg+8m} x 4 classes {cg+32u}
// acc += x * fma(x, w, -2a)  ==  x^2*w - 2*x*a   (no shuffles, LDS broadcast)
__global__ __launch_bounds__(256) void gemm_kernel(
    const float* __restrict__ x, const float* __restrict__ wc,
    const float* __restrict__ a, const unsigned* __restrict__ pres16,
    unsigned* __restrict__ mask, float* __restrict__ part) {
  if (blockIdx.x == 256) {  // merge the 16 presence masks
    if (threadIdx.x < 4) {
      unsigned m = 0;
      #pragma unroll
      for (int bb = 0; bb < 16; bb++) m |= pres16[bb * 4 + threadIdx.x];
      mask[threadIdx.x] = m;
    }
    return;
  }
  __shared__ float xs[MT * XP];     // 25.6 KB
  __shared__ float wcs[NC * CPAD];  // 13.2 KB
  __shared__ float acs[NC * CPAD];  // 13.2 KB
  int t = threadIdx.x;
  int mb = blockIdx.x >> 2;
  int ks = blockIdx.x & 3;

  // stage x-tile (64 rows x 96 cols) via float4
  for (int j = t; j < MT * KT / 4; j += 256) {
    int r = j / 24, c4 = j % 24;
    float4 v = *(const float4*)(x + (mb * MT + r) * ND + ks * KT + c4 * 4);
    *(float4*)(&xs[r * XP + c4 * 4]) = v;
  }

  int cg = t & 31, sg = t >> 5;
  int ku[4];
  #pragma unroll
  for (int u = 0; u < 4; u++) ku[u] = min(cg + 32 * u, NC - 1);

  float acc[8][4];
  #pragma unroll
  for (int m = 0; m < 8; m++)
    #pragma unroll
    for (int u = 0; u < 4; u++) acc[m][u] = 0.f;

  for (int ch = 0; ch < 3; ch++) {
    __syncthreads();
    int koff = ks * KT + ch * 32;
    for (int j = t; j < NC * 32; j += 256) {
      int k = j >> 5, d = j & 31;
      wcs[k * CPAD + d] = wc[k * ND + koff + d];
      acs[k * CPAD + d] = a[k * ND + koff + d];
    }
    __syncthreads();
    #pragma unroll 4
    for (int d = 0; d < 32; d++) {
      float wv[4], m2a[4];
      #pragma unroll
      for (int u = 0; u < 4; u++) {
        wv[u] = wcs[ku[u] * CPAD + d];
        m2a[u] = -2.f * acs[ku[u] * CPAD + d];
      }
      int dcol = ch * 32 + d;
      #pragma unroll
      for (int m = 0; m < 8; m++) {
        float xv = xs[(sg + 8 * m) * XP + dcol];
        #pragma unroll
        for (int u = 0; u < 4; u++) {
          float tv = fmaf(xv, wv[u], m2a[u]);
          acc[m][u] = fmaf(xv, tv, acc[m][u]);
        }
      }
    }
  }

  #pragma unroll
  for (int m = 0; m < 8; m++) {
    int i = mb * MT + sg + 8 * m;
    #pragma unroll
    for (int u = 0; u < 4; u++) {
      int k = cg + 32 * u;
      if (k < NC) part[(ks * NB + i) * PPAD + k] = acc[m][u];
    }
  }
}

// ========== Kernel C: finish (2048 blocks x 256; 2 waves per sample) ==========
__global__ __launch_bounds__(256) void finish_kernel(
    const int* __restrict__ targets, const float* __restrict__ tcc,
    const float* __restrict__ cdist, const unsigned* __restrict__ mask,
    const float* __restrict__ part, float* __restrict__ out) {
  int tid = threadIdx.x;
  int wave = tid >> 6, lane = tid & 63;
  int h = wave & 1, sl = wave >> 1;
  int i = blockIdx.x * 2 + sl;
  int k = h * 64 + lane;
  int ti = targets[i];

  float cand_an = 1e30f, cand_ap = 0.f;
  if (k < NC) {
    float d2 = tcc[k];
    #pragma unroll
    for (int s = 0; s < KS; s++) d2 += part[(s * NB + i) * PPAD + k];
    float dist = sqrtf(fmaxf(d2, 1e-12f));
    bool pres = (mask[k >> 5] >> (k & 31)) & 1u;
    if (k == ti) cand_ap = dist;
    else if (pres) cand_an = dist;
  }
  #pragma unroll
  for (int off = 32; off; off >>= 1) {
    cand_an = fminf(cand_an, __shfl_xor(cand_an, off, 64));
    cand_ap = fmaxf(cand_ap, __shfl_xor(cand_ap, off, 64));
  }
  __shared__ float r_an[2][2], r_ap[2][2];
  if (lane == 0) { r_an[sl][h] = cand_an; r_ap[sl][h] = cand_ap; }
  __syncthreads();
  if (wave == 0) {
    int tl = lane & 1;
    int isamp = blockIdx.x * 2 + tl;
    float cc = cdist[targets[isamp]];
    float an = fminf(r_an[tl][0], r_an[tl][1]);
    float ap = fmaxf(r_ap[tl][0], r_ap[tl][1]);
    float loss = ap + ((an >= cc) ? 0.f : (cc - an));
    float other = __shfl_xor(loss, 1, 64);
    if (lane == 0) atomicAdd(out, (loss + other) * (1.0f / NB));
  }
}

extern "C" void kernel_launch(void* const* d_in, const int* in_sizes, int n_in,
                              void* d_out, int out_size, void* d_ws, size_t ws_size,
                              hipStream_t stream) {
  const float* inputs  = (const float*)d_in[0];
  const int*   targets = (const int*)d_in[1];
  // d_in[2] = epoch_number (unused by the reference math)
  const float* centers = (const float*)d_in[3];
  const float* cw      = (const float*)d_in[4];
  float* out = (float*)d_out;

  float* wc      = (float*)d_ws;               // [100*384]
  float* a       = wc + NC * ND;               // [100*384]
  float* tcc     = a + NC * ND;                // [128]
  float* cdist   = tcc + 128;                  // [128]
  unsigned* pres16 = (unsigned*)(cdist + 128); // [16*4]
  unsigned* mask   = pres16 + 64;              // [4] (padded 64)
  float* part    = (float*)(mask + 64);        // [4*4096*104] = 6.8 MB

  setup_kernel<<<216, 256, 0, stream>>>(centers, cw, targets, wc, a, tcc,
                                        cdist, pres16, out);
  gemm_kernel<<<257, 256, 0, stream>>>(inputs, wc, a, pres16, mask, part);
  finish_kernel<<<NB / 2, 256, 0, stream>>>(targets, tcc, cdist, mask, part, out);
}

// Round 4
// 93.421 us; speedup vs baseline: 2.0299x; 1.3605x over previous
//
#include <hip/hip_runtime.h>
#include <math.h>

#define NC 100
#define ND 384
#define NB 4096
#define KS 4                      // K-split factor
#define KT 96                     // K per split
#define MT 32                     // samples per gemm block
#define XP 100                    // xs row pad (float4-aligned)
#define CPAD 33                   // class-chunk row pad (odd -> conflict-free)
#define PPAD 104                  // partial row pad
#define AUX 116                   // 100 cdist/tcc blocks + 16 presence blocks
#define GEMM_BLOCKS (NB / MT * KS)  // 512

// ================= Kernel 1: fused setup + vector GEMM =================
// blockIdx roles:
//   [0,100)      cdist[i] + tcc[i] for class i (block 0 also zeros out)
//   [100,116)    presence: per-block 128-bit class mask -> pres16
//   [116,628)    gemm: block (mb,ks) computes partial d2 for 32 samples x
//                100 classes over d-range [ks*96, ks*96+96). wc/a computed
//                in-LDS from centers/cw (exp2f at staging time) — no global
//                wc/a round-trip, no dependency on other blocks.
__global__ __launch_bounds__(256) void fused_kernel(
    const float* __restrict__ x, const float* __restrict__ centers,
    const float* __restrict__ cw, const int* __restrict__ targets,
    float* __restrict__ tcc, float* __restrict__ cdist,
    unsigned* __restrict__ pres16, float* __restrict__ part,
    float* __restrict__ out) {
  __shared__ float sA[MT * XP + 2 * NC * CPAD];  // 39.2 KB
  int b = blockIdx.x, tid = threadIdx.x;
  int wave = tid >> 6, lane = tid & 63;

  if (b < NC) {
    // ---- cdist + tcc for class i ----
    int i = b;
    float* ci_s = sA;
    float* wi_s = sA + ND;
    float* sred = sA + 2 * ND;
    if (i == 0 && tid == 255) out[0] = 0.f;  // d_out poisoned each launch
    for (int d = tid; d < ND; d += 256) {
      ci_s[d] = centers[i * ND + d];
      wi_s[d] = exp2f(cw[i * ND + d]);
    }
    __syncthreads();
    {  // tcc[i] = sum_d w*c^2
      float p = 0.f;
      for (int d = tid; d < ND; d += 256) p = fmaf(wi_s[d] * ci_s[d], ci_s[d], p);
      #pragma unroll
      for (int off = 32; off; off >>= 1) p += __shfl_xor(p, off, 64);
      if (lane == 0) sred[wave] = p;
      __syncthreads();
      if (tid == 0) tcc[i] = sred[0] + sred[1] + sred[2] + sred[3];
      __syncthreads();
    }
    float minv = 1e30f;
    for (int s = 0; s < 24; s += 4) {  // wave handles j = wave + 4*s
      float red[4];
      #pragma unroll
      for (int u = 0; u < 4; u++) {
        int j = wave + 4 * (s + u);
        float acc = 0.f;
        #pragma unroll
        for (int e = 0; e < 6; e++) {
          int d = lane + 64 * e;
          float df = ci_s[d] - centers[j * ND + d];
          acc = fmaf(wi_s[d] * df, df, acc);
        }
        red[u] = acc;
      }
      #pragma unroll
      for (int off = 32; off; off >>= 1) {
        #pragma unroll
        for (int u = 0; u < 4; u++) red[u] += __shfl_xor(red[u], off, 64);
      }
      #pragma unroll
      for (int u = 0; u < 4; u++) {
        int j = wave + 4 * (s + u);
        if (j != i) minv = fminf(minv, red[u]);
      }
    }
    {  // tail j = wave + 96
      int j = wave + 96;
      float acc = 0.f;
      #pragma unroll
      for (int e = 0; e < 6; e++) {
        int d = lane + 64 * e;
        float df = ci_s[d] - centers[j * ND + d];
        acc = fmaf(wi_s[d] * df, df, acc);
      }
      #pragma unroll
      for (int off = 32; off; off >>= 1) acc += __shfl_xor(acc, off, 64);
      if (j != i) minv = fminf(minv, acc);
    }
    if (lane == 0) sred[wave] = minv;
    __syncthreads();
    if (tid == 0)
      cdist[i] = sqrtf(fminf(fminf(sred[0], sred[1]), fminf(sred[2], sred[3])));
  } else if (b < AUX) {
    // ---- presence bitmask (per-block local, merged in finish) ----
    int pb = b - NC;
    unsigned* um = (unsigned*)sA;
    if (tid < 4) um[tid] = 0u;
    __syncthreads();
    int t = targets[pb * 256 + tid];
    atomicOr(&um[t >> 5], 1u << (t & 31));
    __syncthreads();
    if (tid < 4) pres16[pb * 4 + tid] = um[tid];
  } else {
    // ---- gemm ----
    int g = b - AUX;
    int mb = g >> 2, ks = g & 3;
    float* xs = sA;                 // [32][100]
    float* wcs = sA + MT * XP;      // [100][33]
    float* acs = wcs + NC * CPAD;   // [100][33]
    int koff0 = ks * KT;

    // stage x-tile (32 rows x 96 cols) via float4
    for (int j = tid; j < MT * KT / 4; j += 256) {
      int r = j / 24, c4 = j - r * 24;
      float4 v = *(const float4*)(x + (mb * MT + r) * ND + koff0 + c4 * 4);
      *(float4*)(&xs[r * XP + c4 * 4]) = v;
    }
    // prefetch chunk 0 (100 classes x 32 d) into registers
    float cwr[13], ccr[13];
    #pragma unroll
    for (int j = 0; j < 13; j++) {
      int idx = tid + 256 * j;
      if (idx < NC * 32) {
        int k = idx >> 5, d = idx & 31;
        cwr[j] = cw[k * ND + koff0 + d];
        ccr[j] = centers[k * ND + koff0 + d];
      }
    }

    int cg = tid & 31, sg = tid >> 5;
    int ku[4];
    #pragma unroll
    for (int u = 0; u < 4; u++) ku[u] = min(cg + 32 * u, NC - 1);
    float acc[4][4];
    #pragma unroll
    for (int m = 0; m < 4; m++)
      #pragma unroll
      for (int u = 0; u < 4; u++) acc[m][u] = 0.f;

    for (int ch = 0; ch < 3; ch++) {
      __syncthreads();
      // write chunk ch to LDS (exp2f fused here; wc/a never touch global)
      #pragma unroll
      for (int j = 0; j < 13; j++) {
        int idx = tid + 256 * j;
        if (idx < NC * 32) {
          int k = idx >> 5, d = idx & 31;
          float w = exp2f(cwr[j]);
          wcs[k * CPAD + d] = w;
          acs[k * CPAD + d] = w * ccr[j];
        }
      }
      __syncthreads();
      if (ch < 2) {  // prefetch next chunk; loads fly during compute below
        int koff = koff0 + (ch + 1) * 32;
        #pragma unroll
        for (int j = 0; j < 13; j++) {
          int idx = tid + 256 * j;
          if (idx < NC * 32) {
            int k = idx >> 5, d = idx & 31;
            cwr[j] = cw[k * ND + koff + d];
            ccr[j] = centers[k * ND + koff + d];
          }
        }
      }
      int dbase = ch * 32;
      #pragma unroll 4
      for (int d = 0; d < 32; d++) {
        float wv[4], m2a[4];
        #pragma unroll
        for (int u = 0; u < 4; u++) {
          wv[u] = wcs[ku[u] * CPAD + d];        // conflict-free (odd stride)
          m2a[u] = -2.f * acs[ku[u] * CPAD + d];
        }
        int dcol = dbase + d;
        #pragma unroll
        for (int m = 0; m < 4; m++) {
          float xv = xs[(sg + 8 * m) * XP + dcol];  // broadcast read
          #pragma unroll
          for (int u = 0; u < 4; u++)
            acc[m][u] = fmaf(xv, fmaf(xv, wv[u], m2a[u]), acc[m][u]);
        }
      }
    }
    #pragma unroll
    for (int m = 0; m < 4; m++) {
      int i = mb * MT + sg + 8 * m;
      #pragma unroll
      for (int u = 0; u < 4; u++) {
        int k = cg + 32 * u;
        if (k < NC) part[(ks * NB + i) * PPAD + k] = acc[m][u];
      }
    }
  }
}

// ========== Kernel 2: finish (512 blocks; 8 samples/block; 1 atomic/block) ==========
__global__ __launch_bounds__(256) void finish_kernel(
    const int* __restrict__ targets, const float* __restrict__ tcc,
    const float* __restrict__ cdist, const unsigned* __restrict__ pres16,
    const float* __restrict__ part, float* __restrict__ out) {
  __shared__ unsigned msk[4];
  __shared__ float r_an[2][2], r_ap[2][2], lsum[8];
  int tid = threadIdx.x;
  if (tid < 4) {
    unsigned m = 0;
    #pragma unroll
    for (int bb = 0; bb < 16; bb++) m |= pres16[bb * 4 + tid];
    msk[tid] = m;
  }
  int wave = tid >> 6, lane = tid & 63;
  int h = wave & 1, sl = wave >> 1;
  int k = h * 64 + lane;
  bool valid = k < NC;
  float base = valid ? tcc[k] : 0.f;
  __syncthreads();
  bool pres = valid && ((msk[k >> 5] >> (k & 31)) & 1u);

  for (int pass = 0; pass < 4; pass++) {
    int i = blockIdx.x * 8 + pass * 2 + sl;
    int ti = targets[i];
    float cand_an = 1e30f, cand_ap = 0.f;
    if (valid) {
      float d2 = base;
      #pragma unroll
      for (int s = 0; s < KS; s++) d2 += part[(s * NB + i) * PPAD + k];
      float dist = sqrtf(fmaxf(d2, 1e-12f));
      if (k == ti) cand_ap = dist;
      else if (pres) cand_an = dist;
    }
    #pragma unroll
    for (int off = 32; off; off >>= 1) {
      cand_an = fminf(cand_an, __shfl_xor(cand_an, off, 64));
      cand_ap = fmaxf(cand_ap, __shfl_xor(cand_ap, off, 64));
    }
    if (lane == 0) { r_an[sl][h] = cand_an; r_ap[sl][h] = cand_ap; }
    __syncthreads();
    if (tid < 2) {
      int isamp = blockIdx.x * 8 + pass * 2 + tid;
      float cc = cdist[targets[isamp]];
      float an = fminf(r_an[tid][0], r_an[tid][1]);
      float ap = fmaxf(r_ap[tid][0], r_ap[tid][1]);
      lsum[pass * 2 + tid] = ap + ((an >= cc) ? 0.f : cc - an);
    }
    __syncthreads();  // r_an/r_ap reused next pass
  }
  if (tid == 0) {
    float t = 0.f;
    #pragma unroll
    for (int j = 0; j < 8; j++) t += lsum[j];
    atomicAdd(out, t * (1.0f / NB));
  }
}

extern "C" void kernel_launch(void* const* d_in, const int* in_sizes, int n_in,
                              void* d_out, int out_size, void* d_ws, size_t ws_size,
                              hipStream_t stream) {
  const float* inputs  = (const float*)d_in[0];
  const int*   targets = (const int*)d_in[1];
  // d_in[2] = epoch_number (unused by the reference math)
  const float* centers = (const float*)d_in[3];
  const float* cw      = (const float*)d_in[4];
  float* out = (float*)d_out;

  float* tcc       = (float*)d_ws;                 // [128]
  float* cdist     = tcc + 128;                    // [128]
  unsigned* pres16 = (unsigned*)(cdist + 128);     // [64]
  float* part      = (float*)(pres16 + 64);        // [4*4096*104] = 6.8 MB

  fused_kernel<<<AUX + GEMM_BLOCKS, 256, 0, stream>>>(
      inputs, centers, cw, targets, tcc, cdist, pres16, part, out);
  finish_kernel<<<NB / 8, 256, 0, stream>>>(targets, tcc, cdist, pres16, part, out);
}